// Round 2
// baseline (498.540 us; speedup 1.0000x reference)
//
#include <hip/hip_runtime.h>

// NonLocalBlock: B=8, C=512, N=4096 (64x64), CR=128.
// ws layout (bf16): ab [8][4096][256] (emb_a 0..127, emb_b 128..255, token-major)
//                   gC [8][128][4096] (channel-major)
//                   yt [8][4096][128] (token-major)

typedef __attribute__((ext_vector_type(8))) short short8;
typedef __attribute__((ext_vector_type(4))) float f32x4;

__device__ inline unsigned short f2bf(float f) {
  union { float f; unsigned u; } v; v.f = f;
  unsigned u = v.u;
  unsigned r = u + 0x7FFFu + ((u >> 16) & 1u);   // RNE
  return (unsigned short)(r >> 16);
}
__device__ inline unsigned pack2(float a, float b) {
  return (unsigned)f2bf(a) | ((unsigned)f2bf(b) << 16);
}
// XOR-swizzled LDS index (halves). 16B groups: phys_group = logical_group ^ (row&7).
__device__ inline int sw(int row, int col, int stride_halves) {
  return row * stride_halves + ((((col >> 3) ^ (row & 7)) << 3) | (col & 7));
}

// ---------------- kernel 1: in-projection GEMM (M=384, K=512, N=4096, per batch) ----
__global__ __launch_bounds__(256) void k_proj(const float* __restrict__ x,
                                              const float* __restrict__ w_in,
                                              unsigned short* __restrict__ ab,
                                              unsigned short* __restrict__ gC) {
  __shared__ unsigned short A_lds[128 * 64];   // w_in tile [128 o][64 c], swizzled
  __shared__ unsigned short B_lds[64 * 64];    // x^T tile  [64 n][64 c], swizzled
  const int t = threadIdx.x;
  const int lane = t & 63;
  const int w = t >> 6;
  const int l15 = lane & 15;
  const int quad = lane >> 4;
  const int l7 = l15 & 7;
  const int n0 = blockIdx.x * 64;
  const int o0 = blockIdx.y * 128;
  const int b = blockIdx.z;
  const int ch8g = t >> 5;        // 0..7: 8-channel group for B staging
  const int tp = t & 31;          // 0..31: token pair

  f32x4 acc[2][4];
#pragma unroll
  for (int i = 0; i < 2; i++)
#pragma unroll
    for (int j = 0; j < 4; j++) acc[i][j] = (f32x4)0.f;

  for (int k0 = 0; k0 < 512; k0 += 64) {
    // stage A: w_in[o0+row][k0 + v*4], fp32 -> bf16, swizzled uint2 writes
#pragma unroll
    for (int i = 0; i < 8; i++) {
      int idx = t + i * 256;
      int row = idx >> 4, v = idx & 15;
      const float4 d = *(const float4*)&w_in[(size_t)(o0 + row) * 512 + k0 + v * 4];
      uint2 p; p.x = pack2(d.x, d.y); p.y = pack2(d.z, d.w);
      *(uint2*)&A_lds[sw(row, v * 4, 64)] = p;
    }
    // stage B micro-transpose: 8 channels x 2 tokens per thread
    {
      float2 d[8];
#pragma unroll
      for (int j = 0; j < 8; j++)
        d[j] = *(const float2*)&x[((size_t)(b * 512 + k0 + ch8g * 8 + j)) * 4096 + n0 + tp * 2];
#pragma unroll
      for (int i = 0; i < 2; i++) {
        int r = tp * 2 + i;
        uint4 pv;
        if (i == 0) {
          pv.x = pack2(d[0].x, d[1].x); pv.y = pack2(d[2].x, d[3].x);
          pv.z = pack2(d[4].x, d[5].x); pv.w = pack2(d[6].x, d[7].x);
        } else {
          pv.x = pack2(d[0].y, d[1].y); pv.y = pack2(d[2].y, d[3].y);
          pv.z = pack2(d[4].y, d[5].y); pv.w = pack2(d[6].y, d[7].y);
        }
        *(uint4*)&B_lds[sw(r, ch8g * 8, 64)] = pv;
      }
    }
    __syncthreads();
#pragma unroll
    for (int kk = 0; kk < 64; kk += 32) {
      short8 a0 = *(const short8*)&A_lds[sw(w * 32 + l15, kk + quad * 8, 64)];
      short8 a1 = *(const short8*)&A_lds[sw(w * 32 + 16 + l15, kk + quad * 8, 64)];
#pragma unroll
      for (int ns = 0; ns < 4; ns++) {
        short8 bb = *(const short8*)&B_lds[sw(ns * 16 + l15, kk + quad * 8, 64)];
        acc[0][ns] = __builtin_amdgcn_mfma_f32_16x16x32_bf16(a0, bb, acc[0][ns], 0, 0, 0);
        acc[1][ns] = __builtin_amdgcn_mfma_f32_16x16x32_bf16(a1, bb, acc[1][ns], 0, 0, 0);
      }
    }
    __syncthreads();
  }
  // epilogue: C/D layout col=lane&15 (=n), row=quad*4+reg (=o)
  if (o0 < 256) {
#pragma unroll
    for (int ms = 0; ms < 2; ms++) {
      int o = o0 + w * 32 + ms * 16 + quad * 4;
#pragma unroll
      for (int ns = 0; ns < 4; ns++) {
        int n = n0 + ns * 16 + l15;
        uint2 p;
        p.x = pack2(acc[ms][ns][0], acc[ms][ns][1]);
        p.y = pack2(acc[ms][ns][2], acc[ms][ns][3]);
        *(uint2*)&ab[((size_t)(b * 4096 + n)) * 256 + o] = p;   // token-major
      }
    }
  } else {
#pragma unroll
    for (int ms = 0; ms < 2; ms++) {
      int og = w * 32 + ms * 16 + quad * 4;   // g channel index
#pragma unroll
      for (int ns = 0; ns < 4; ns++) {
        int n = n0 + ns * 16 + l15;
#pragma unroll
        for (int r = 0; r < 4; r++)
          gC[((size_t)(b * 128 + og + r)) * 4096 + n] = f2bf(acc[ms][ns][r]);
      }
    }
  }
}

// ---------------- kernel 2: flash attention, BQ=64 (16 q/wave), BK=64 keys ----------
// Q fragments in registers; K/V register-prefetch pipeline; swizzled unpadded LDS.
__global__ __launch_bounds__(256, 3) void k_attn(const unsigned short* __restrict__ ab,
                                                 const unsigned short* __restrict__ gC,
                                                 unsigned short* __restrict__ yt) {
  __shared__ unsigned short K_lds[64 * 128];    // [key][128 c], swizzled (16 KB)
  __shared__ unsigned short V_lds[128 * 64];    // [c'][64 key], swizzled (16 KB)
  __shared__ unsigned short P_lds[4 * 16 * 64]; // per-wave [16 q][64 key], swizzled (8 KB)
  const int t = threadIdx.x;
  const int lane = t & 63;
  const int w = t >> 6;
  const int l15 = lane & 15;
  const int quad = lane >> 4;
  const int l7 = l15 & 7;
  const int q0 = blockIdx.x * 64;
  const int b = blockIdx.y;

  // Q fragments: loop-invariant, straight from global (token-major, 16B/lane)
  short8 qf[4];
  {
    const unsigned short* qp = &ab[((size_t)(b * 4096 + q0 + w * 16 + l15)) * 256 + quad * 8];
    qf[0] = *(const short8*)&qp[0];
    qf[1] = *(const short8*)&qp[32];
    qf[2] = *(const short8*)&qp[64];
    qf[3] = *(const short8*)&qp[96];
  }

  uint4 kreg[4], vreg[4];
  auto load_tiles = [&](int kt) {
#pragma unroll
    for (int i = 0; i < 4; i++) {
      int idx = t + i * 256;
      int row = idx >> 4, v = idx & 15;
      kreg[i] = *(const uint4*)&ab[((size_t)(b * 4096 + kt + row)) * 256 + 128 + v * 8];
    }
#pragma unroll
    for (int i = 0; i < 4; i++) {
      int idx = t + i * 256;
      int row = idx >> 3, v = idx & 7;
      vreg[i] = *(const uint4*)&gC[((size_t)(b * 128 + row)) * 4096 + kt + v * 8];
    }
  };

  f32x4 O[8];
#pragma unroll
  for (int i = 0; i < 8; i++) O[i] = (f32x4)0.f;
  float mcur = -INFINITY, lsum = 0.f;

  load_tiles(0);   // preload tile 0 into registers

  for (int kt0 = 0; kt0 < 4096; kt0 += 64) {
    __syncthreads();   // all waves done reading previous tile's LDS
    // store prefetched tile (compiler waits vmcnt here; loads issued one compute-phase ago)
#pragma unroll
    for (int i = 0; i < 4; i++) {
      int idx = t + i * 256;
      int row = idx >> 4, v = idx & 15;
      *(uint4*)&K_lds[sw(row, v * 8, 128)] = kreg[i];
    }
#pragma unroll
    for (int i = 0; i < 4; i++) {
      int idx = t + i * 256;
      int row = idx >> 3, v = idx & 7;
      *(uint4*)&V_lds[sw(row, v * 8, 64)] = vreg[i];
    }
    __syncthreads();
    if (kt0 + 64 < 4096) load_tiles(kt0 + 64);   // issue next tile's loads (async)

    // S^T = K · Q^T  -> D[key][q]: lane owns q col l15, 4 consecutive keys/reg
    f32x4 accS[4];
#pragma unroll
    for (int i = 0; i < 4; i++) accS[i] = (f32x4)0.f;
#pragma unroll
    for (int ks = 0; ks < 4; ks++) {
#pragma unroll
      for (int mt = 0; mt < 4; mt++) {
        short8 ak = *(const short8*)&K_lds[sw(mt * 16 + l15, ks * 32 + quad * 8, 128)];
        accS[mt] = __builtin_amdgcn_mfma_f32_16x16x32_bf16(ak, qf[ks], accS[mt], 0, 0, 0);
      }
    }

    // online softmax: stats per q=l15; reduce across quads (xor 16, 32)
    float smax = -INFINITY;
#pragma unroll
    for (int mt = 0; mt < 4; mt++)
#pragma unroll
      for (int r = 0; r < 4; r++) smax = fmaxf(smax, accS[mt][r]);
    smax = fmaxf(smax, __shfl_xor(smax, 16));
    smax = fmaxf(smax, __shfl_xor(smax, 32));
    float mnew = fmaxf(mcur, smax);
    float alpha = __expf(mcur - mnew);   // first iter: exp(-inf)=0
    float rsum = 0.f;
#pragma unroll
    for (int mt = 0; mt < 4; mt++) {
#pragma unroll
      for (int r = 0; r < 4; r++) {
        float p = __expf(accS[mt][r] - mnew);
        accS[mt][r] = p;
        rsum += p;
      }
    }
    rsum += __shfl_xor(rsum, 16);
    rsum += __shfl_xor(rsum, 32);
    lsum = lsum * alpha + rsum;
    mcur = mnew;

    // rescale O: O rows are q = quad*4+r; alpha lives at lane col q
#pragma unroll
    for (int r = 0; r < 4; r++) {
      float ar = __shfl(alpha, quad * 4 + r);
#pragma unroll
      for (int ct = 0; ct < 8; ct++) O[ct][r] *= ar;
    }

    // write P^T -> per-wave P_lds[q][key] (swizzled); 4 consecutive keys -> one b64
#pragma unroll
    for (int mt = 0; mt < 4; mt++) {
      uint2 p;
      p.x = pack2(accS[mt][0], accS[mt][1]);
      p.y = pack2(accS[mt][2], accS[mt][3]);
      *(uint2*)&P_lds[w * 16 * 64 + sw(l15, mt * 16 + quad * 4, 64)] = p;
    }

    // O[q][c'] += P · V
#pragma unroll
    for (int ks2 = 0; ks2 < 2; ks2++) {
      short8 ap = *(const short8*)&P_lds[w * 16 * 64 + sw(l15, ks2 * 32 + quad * 8, 64)];
#pragma unroll
      for (int ct = 0; ct < 8; ct++) {
        short8 bv = *(const short8*)&V_lds[sw(ct * 16 + l15, ks2 * 32 + quad * 8, 64)];
        O[ct] = __builtin_amdgcn_mfma_f32_16x16x32_bf16(ap, bv, O[ct], 0, 0, 0);
      }
    }
  }

  // epilogue: y = O / l; O rows q = quad*4+r, cols c' = ct*16+l15
  float linv = 1.f / lsum;
#pragma unroll
  for (int r = 0; r < 4; r++) {
    float lr = __shfl(linv, quad * 4 + r);
    int tok = q0 + w * 16 + quad * 4 + r;
#pragma unroll
    for (int ct = 0; ct < 8; ct++)
      yt[((size_t)(b * 4096 + tok)) * 128 + ct * 16 + l15] = f2bf(O[ct][r] * lr);
  }
}

// ---------------- kernel 3: out-projection GEMM (M=512, K=128, N=4096) + residual ---
__global__ __launch_bounds__(256) void k_out(const float* __restrict__ x,
                                             const float* __restrict__ w_out,
                                             const unsigned short* __restrict__ yt,
                                             float* __restrict__ out) {
  __shared__ unsigned short A_lds[128 * 136];  // w_out tile [128 o][128 c + pad8]
  __shared__ unsigned short B_lds[64 * 136];   // y tile [64 n][128 c + pad8]
  const int t = threadIdx.x;
  const int lane = t & 63;
  const int w = t >> 6;
  const int l15 = lane & 15;
  const int quad = lane >> 4;
  const int n0 = blockIdx.x * 64;
  const int o0 = blockIdx.y * 128;
  const int b = blockIdx.z;

#pragma unroll
  for (int i = 0; i < 16; i++) {
    int idx = t + i * 256;
    int row = idx >> 5, v = idx & 31;
    const float4 d = *(const float4*)&w_out[(size_t)(o0 + row) * 128 + v * 4];
    uint2 p; p.x = pack2(d.x, d.y); p.y = pack2(d.z, d.w);
    *(uint2*)&A_lds[row * 136 + v * 4] = p;
  }
#pragma unroll
  for (int i = 0; i < 4; i++) {
    int idx = t + i * 256;
    int row = idx >> 4, v = idx & 15;
    *(uint4*)&B_lds[row * 136 + v * 8] =
        *(const uint4*)&yt[((size_t)(b * 4096 + n0 + row)) * 128 + v * 8];
  }
  __syncthreads();

  f32x4 acc[2][4];
#pragma unroll
  for (int i = 0; i < 2; i++)
#pragma unroll
    for (int j = 0; j < 4; j++) acc[i][j] = (f32x4)0.f;
#pragma unroll
  for (int ks = 0; ks < 4; ks++) {
    short8 a0 = *(const short8*)&A_lds[(w * 32 + l15) * 136 + ks * 32 + quad * 8];
    short8 a1 = *(const short8*)&A_lds[(w * 32 + 16 + l15) * 136 + ks * 32 + quad * 8];
#pragma unroll
    for (int ns = 0; ns < 4; ns++) {
      short8 bb = *(const short8*)&B_lds[(ns * 16 + l15) * 136 + ks * 32 + quad * 8];
      acc[0][ns] = __builtin_amdgcn_mfma_f32_16x16x32_bf16(a0, bb, acc[0][ns], 0, 0, 0);
      acc[1][ns] = __builtin_amdgcn_mfma_f32_16x16x32_bf16(a1, bb, acc[1][ns], 0, 0, 0);
    }
  }
#pragma unroll
  for (int ms = 0; ms < 2; ms++) {
    int o = o0 + w * 32 + ms * 16 + quad * 4;
#pragma unroll
    for (int ns = 0; ns < 4; ns++) {
      int n = n0 + ns * 16 + l15;
#pragma unroll
      for (int r = 0; r < 4; r++) {
        size_t off = ((size_t)(b * 512 + o + r)) * 4096 + n;
        out[off] = x[off] + acc[ms][ns][r];
      }
    }
  }
}

extern "C" void kernel_launch(void* const* d_in, const int* in_sizes, int n_in,
                              void* d_out, int out_size, void* d_ws, size_t ws_size,
                              hipStream_t stream) {
  const float* x = (const float*)d_in[0];
  const float* w_in = (const float*)d_in[1];
  const float* w_out = (const float*)d_in[2];
  float* out = (float*)d_out;

  unsigned short* ab = (unsigned short*)d_ws;                 // 8*4096*256 bf16
  unsigned short* gC = ab + (size_t)8 * 4096 * 256;           // 8*128*4096 bf16
  unsigned short* yt = gC + (size_t)8 * 128 * 4096;           // 8*4096*128 bf16

  k_proj<<<dim3(64, 3, 8), 256, 0, stream>>>(x, w_in, ab, gC);
  k_attn<<<dim3(64, 8), 256, 0, stream>>>(ab, gC, yt);
  k_out<<<dim3(64, 4, 8), 256, 0, stream>>>(x, w_out, yt, out);
}

// Round 3
// 344.774 us; speedup vs baseline: 1.4460x; 1.4460x over previous
//
#include <hip/hip_runtime.h>

// NonLocalBlock: B=8, C=512, N=4096 (64x64), CR=128.
// ws layout (bf16): ab [8][4096][256] (emb_a 0..127, emb_b 128..255, token-major)
//                   gC [8][128][4096] (channel-major)
//                   yt [8][4096][128] (token-major)

typedef __attribute__((ext_vector_type(8))) short short8;
typedef __attribute__((ext_vector_type(4))) float f32x4;
typedef __attribute__((ext_vector_type(16))) float f32x16;

__device__ inline unsigned short f2bf(float f) {
  union { float f; unsigned u; } v; v.f = f;
  unsigned u = v.u;
  unsigned r = u + 0x7FFFu + ((u >> 16) & 1u);   // RNE
  return (unsigned short)(r >> 16);
}
__device__ inline unsigned pack2(float a, float b) {
  return (unsigned)f2bf(a) | ((unsigned)f2bf(b) << 16);
}
// XOR-swizzled LDS index (halves). 16B granules: phys = g ^ (row&7).
__device__ inline int sw(int row, int col, int stride_halves) {
  return row * stride_halves + ((((col >> 3) ^ (row & 7)) << 3) | (col & 7));
}

// ---------------- kernel 1: in-projection GEMM (M=384, K=512, N=4096, per batch) ----
__global__ __launch_bounds__(256) void k_proj(const float* __restrict__ x,
                                              const float* __restrict__ w_in,
                                              unsigned short* __restrict__ ab,
                                              unsigned short* __restrict__ gC) {
  __shared__ unsigned short A_lds[128 * 64];   // w_in tile [128 o][64 c], swizzled
  __shared__ unsigned short B_lds[64 * 64];    // x^T tile  [64 n][64 c], swizzled
  const int t = threadIdx.x;
  const int lane = t & 63;
  const int w = t >> 6;
  const int l15 = lane & 15;
  const int quad = lane >> 4;
  const int n0 = blockIdx.x * 64;
  const int o0 = blockIdx.y * 128;
  const int b = blockIdx.z;
  const int ch8g = t >> 5;        // 0..7: 8-channel group for B staging
  const int tp = t & 31;          // 0..31: token pair

  f32x4 acc[2][4];
#pragma unroll
  for (int i = 0; i < 2; i++)
#pragma unroll
    for (int j = 0; j < 4; j++) acc[i][j] = (f32x4)0.f;

  for (int k0 = 0; k0 < 512; k0 += 64) {
#pragma unroll
    for (int i = 0; i < 8; i++) {
      int idx = t + i * 256;
      int row = idx >> 4, v = idx & 15;
      const float4 d = *(const float4*)&w_in[(size_t)(o0 + row) * 512 + k0 + v * 4];
      uint2 p; p.x = pack2(d.x, d.y); p.y = pack2(d.z, d.w);
      *(uint2*)&A_lds[sw(row, v * 4, 64)] = p;
    }
    {
      float2 d[8];
#pragma unroll
      for (int j = 0; j < 8; j++)
        d[j] = *(const float2*)&x[((size_t)(b * 512 + k0 + ch8g * 8 + j)) * 4096 + n0 + tp * 2];
#pragma unroll
      for (int i = 0; i < 2; i++) {
        int r = tp * 2 + i;
        uint4 pv;
        if (i == 0) {
          pv.x = pack2(d[0].x, d[1].x); pv.y = pack2(d[2].x, d[3].x);
          pv.z = pack2(d[4].x, d[5].x); pv.w = pack2(d[6].x, d[7].x);
        } else {
          pv.x = pack2(d[0].y, d[1].y); pv.y = pack2(d[2].y, d[3].y);
          pv.z = pack2(d[4].y, d[5].y); pv.w = pack2(d[6].y, d[7].y);
        }
        *(uint4*)&B_lds[sw(r, ch8g * 8, 64)] = pv;
      }
    }
    __syncthreads();
#pragma unroll
    for (int kk = 0; kk < 64; kk += 32) {
      short8 a0 = *(const short8*)&A_lds[sw(w * 32 + l15, kk + quad * 8, 64)];
      short8 a1 = *(const short8*)&A_lds[sw(w * 32 + 16 + l15, kk + quad * 8, 64)];
#pragma unroll
      for (int ns = 0; ns < 4; ns++) {
        short8 bb = *(const short8*)&B_lds[sw(ns * 16 + l15, kk + quad * 8, 64)];
        acc[0][ns] = __builtin_amdgcn_mfma_f32_16x16x32_bf16(a0, bb, acc[0][ns], 0, 0, 0);
        acc[1][ns] = __builtin_amdgcn_mfma_f32_16x16x32_bf16(a1, bb, acc[1][ns], 0, 0, 0);
      }
    }
    __syncthreads();
  }
  if (o0 < 256) {
#pragma unroll
    for (int ms = 0; ms < 2; ms++) {
      int o = o0 + w * 32 + ms * 16 + quad * 4;
#pragma unroll
      for (int ns = 0; ns < 4; ns++) {
        int n = n0 + ns * 16 + l15;
        uint2 p;
        p.x = pack2(acc[ms][ns][0], acc[ms][ns][1]);
        p.y = pack2(acc[ms][ns][2], acc[ms][ns][3]);
        *(uint2*)&ab[((size_t)(b * 4096 + n)) * 256 + o] = p;
      }
    }
  } else {
#pragma unroll
    for (int ms = 0; ms < 2; ms++) {
      int og = w * 32 + ms * 16 + quad * 4;
#pragma unroll
      for (int ns = 0; ns < 4; ns++) {
        int n = n0 + ns * 16 + l15;
#pragma unroll
        for (int r = 0; r < 4; r++)
          gC[((size_t)(b * 128 + og + r)) * 4096 + n] = f2bf(acc[ms][ns][r]);
      }
    }
  }
}

// ---------------- kernel 2: flash attention, 32x32x16 MFMA, no-max softmax ---------
// Wave (wr=w&1, wc=w>>1): S^T tile [32 keys (wr half)][32 q (wc half)].
// O^T partial per wave over its key-half; merged once in epilogue (no per-iter rescale).
__global__ __launch_bounds__(256, 2) void k_attn(const unsigned short* __restrict__ ab,
                                                 const unsigned short* __restrict__ gC,
                                                 unsigned short* __restrict__ yt) {
  __shared__ uint4 smem4[49920 / 16];
  unsigned short* K_lds = (unsigned short*)smem4;            // [64 key][128 c] swizz, 16 KB
  unsigned short* V_lds = (unsigned short*)smem4 + 64 * 128; // [128 c][64 key] swizz, 16 KB
  float* Obuf = (float*)smem4;                               // [64 q][129 c] f32 (epilogue)
  float* lsumbuf = (float*)((char*)smem4 + 33024);           // [64]
  unsigned* Pbuf = (unsigned*)((char*)smem4 + 33280);        // [64 q][65] bf16-pairs

  const int t = threadIdx.x;
  const int lane = t & 63;
  const int w = t >> 6;
  const int wr = w & 1;        // key half
  const int wc = w >> 1;       // q half
  const int l31 = lane & 31;
  const int h = lane >> 5;
  const int q0 = blockIdx.x * 64;
  const int b = blockIdx.y;

  // Q fragments (B operand), loop-invariant: B[k=h*8+j][n=q=l31], kbase=ks*16
  short8 qf[8];
  {
    const unsigned short* qp = &ab[((size_t)(b * 4096 + q0 + wc * 32 + l31)) * 256 + h * 8];
#pragma unroll
    for (int ks = 0; ks < 8; ks++) qf[ks] = *(const short8*)&qp[ks * 16];
  }

  // staging geometry (constant per thread)
  const int krow = t >> 2, kgb = (t & 3) * 4;          // K: 4 granules of row krow
  const int vrow = t >> 1, vgb = (t & 1) * 4;          // V: 4 granules of row vrow
  const unsigned short* kgptr = &ab[((size_t)(b * 4096 + krow)) * 256 + 128];
  const unsigned short* vgptr = &gC[((size_t)(b * 128 + vrow)) * 4096];
  int kwoff[4], vwoff[4];
#pragma unroll
  for (int i = 0; i < 4; i++) {
    kwoff[i] = krow * 128 + (((kgb + i) ^ (krow & 7)) << 3);
    vwoff[i] = vrow * 64 + (((vgb + i) ^ (vrow & 7)) << 3);
  }

  f32x16 O[4];
#pragma unroll
  for (int i = 0; i < 4; i++) O[i] = (f32x16)0.f;
  float lsum = 0.f;

  const int rowK = wr * 32 + l31;
  const int l7 = l31 & 7;

  for (int kt0 = 0; kt0 < 4096; kt0 += 64) {
    uint4 kreg[4], vreg[4];
    const unsigned short* kp = kgptr + (size_t)kt0 * 256;
#pragma unroll
    for (int i = 0; i < 4; i++) kreg[i] = *(const uint4*)&kp[(kgb + i) * 8];
    const unsigned short* vp = vgptr + kt0;
#pragma unroll
    for (int i = 0; i < 4; i++) vreg[i] = *(const uint4*)&vp[(vgb + i) * 8];
#pragma unroll
    for (int i = 0; i < 4; i++) *(uint4*)&K_lds[kwoff[i]] = kreg[i];
#pragma unroll
    for (int i = 0; i < 4; i++) *(uint4*)&V_lds[vwoff[i]] = vreg[i];
    __syncthreads();

    // S^T = K · Q^T : D[key local 32][q 32], 8 MFMA
    f32x16 accS = (f32x16)0.f;
#pragma unroll
    for (int ks = 0; ks < 8; ks++) {
      short8 ak = *(const short8*)&K_lds[rowK * 128 + (((ks * 2 + h) ^ l7) << 3)];
      accS = __builtin_amdgcn_mfma_f32_32x32x16_bf16(ak, qf[ks], accS, 0, 0, 0);
    }

    // exp (no max) + lsum partial; pack pairs (reg r -> key (r&3)+8*(r>>2)+4h)
    float ps[16];
#pragma unroll
    for (int r = 0; r < 16; r++) {
      ps[r] = __expf(accS[r]);
      lsum += ps[r];
    }
    unsigned u[8];
#pragma unroll
    for (int i = 0; i < 8; i++) u[i] = pack2(ps[2 * i], ps[2 * i + 1]);

    // build P^T B-frags in-register: frag f covers keys (rel) f*16 + h*8 + j
    short8 pfrag[2];
#pragma unroll
    for (int f = 0; f < 2; f++) {
      unsigned a0 = u[4 * f + 0], a1 = u[4 * f + 1], a2 = u[4 * f + 2], a3 = u[4 * f + 3];
      unsigned r0 = __shfl_xor(h ? a0 : a2, 32);
      unsigned r1 = __shfl_xor(h ? a1 : a3, 32);
      union { unsigned uu[4]; short8 s; } cv;
      if (h == 0) { cv.uu[0] = a0; cv.uu[1] = a1; cv.uu[2] = r0; cv.uu[3] = r1; }
      else        { cv.uu[0] = r0; cv.uu[1] = r1; cv.uu[2] = a2; cv.uu[3] = a3; }
      pfrag[f] = cv.s;
    }

    // O^T[c][q] += V · P^T over this wave's 32 keys: 8 MFMA
#pragma unroll
    for (int ct = 0; ct < 4; ct++) {
      int rowV = ct * 32 + l31;
#pragma unroll
      for (int f = 0; f < 2; f++) {
        short8 av = *(const short8*)&V_lds[rowV * 64 + (((wr * 4 + f * 2 + h) ^ l7) << 3)];
        O[ct] = __builtin_amdgcn_mfma_f32_32x32x16_bf16(av, pfrag[f], O[ct], 0, 0, 0);
      }
    }
    __syncthreads();
  }

  // ---- epilogue: merge key-half partials, normalize, coalesced store ----
  lsum += __shfl_xor(lsum, 32);          // combine h halves (same q column)
  const int q = wc * 32 + l31;
  if (wr == 0) {
#pragma unroll
    for (int ct = 0; ct < 4; ct++)
#pragma unroll
      for (int r = 0; r < 16; r++) {
        int c = ct * 32 + (r & 3) + 8 * (r >> 2) + 4 * h;
        Obuf[q * 129 + c] = O[ct][r];
      }
    if (h == 0) lsumbuf[q] = lsum;
  }
  __syncthreads();
  if (wr == 1) {
    float linv = 1.f / (lsum + lsumbuf[q]);
#pragma unroll
    for (int ct = 0; ct < 4; ct++)
#pragma unroll
      for (int r = 0; r < 16; r += 2) {
        int c = ct * 32 + (r & 3) + 8 * (r >> 2) + 4 * h;
        float v0 = (Obuf[q * 129 + c] + O[ct][r]) * linv;
        float v1 = (Obuf[q * 129 + c + 1] + O[ct][r + 1]) * linv;
        Pbuf[q * 65 + (c >> 1)] = pack2(v0, v1);
      }
  }
  __syncthreads();
  {
    int qq = t >> 2, seg = t & 3;
    unsigned* yrow = (unsigned*)&yt[((size_t)(b * 4096 + q0 + qq)) * 128];
#pragma unroll
    for (int i = 0; i < 4; i++) {
      uint4 v;
      v.x = Pbuf[qq * 65 + seg * 16 + i * 4 + 0];
      v.y = Pbuf[qq * 65 + seg * 16 + i * 4 + 1];
      v.z = Pbuf[qq * 65 + seg * 16 + i * 4 + 2];
      v.w = Pbuf[qq * 65 + seg * 16 + i * 4 + 3];
      *(uint4*)&yrow[seg * 16 + i * 4] = v;
    }
  }
}

// ---------------- kernel 3: out-projection GEMM (M=512, K=128, N=4096) + residual ---
__global__ __launch_bounds__(256) void k_out(const float* __restrict__ x,
                                             const float* __restrict__ w_out,
                                             const unsigned short* __restrict__ yt,
                                             float* __restrict__ out) {
  __shared__ unsigned short A_lds[128 * 136];
  __shared__ unsigned short B_lds[64 * 136];
  const int t = threadIdx.x;
  const int lane = t & 63;
  const int w = t >> 6;
  const int l15 = lane & 15;
  const int quad = lane >> 4;
  const int n0 = blockIdx.x * 64;
  const int o0 = blockIdx.y * 128;
  const int b = blockIdx.z;

#pragma unroll
  for (int i = 0; i < 16; i++) {
    int idx = t + i * 256;
    int row = idx >> 5, v = idx & 31;
    const float4 d = *(const float4*)&w_out[(size_t)(o0 + row) * 128 + v * 4];
    uint2 p; p.x = pack2(d.x, d.y); p.y = pack2(d.z, d.w);
    *(uint2*)&A_lds[row * 136 + v * 4] = p;
  }
#pragma unroll
  for (int i = 0; i < 4; i++) {
    int idx = t + i * 256;
    int row = idx >> 4, v = idx & 15;
    *(uint4*)&B_lds[row * 136 + v * 8] =
        *(const uint4*)&yt[((size_t)(b * 4096 + n0 + row)) * 128 + v * 8];
  }
  __syncthreads();

  f32x4 acc[2][4];
#pragma unroll
  for (int i = 0; i < 2; i++)
#pragma unroll
    for (int j = 0; j < 4; j++) acc[i][j] = (f32x4)0.f;
#pragma unroll
  for (int ks = 0; ks < 4; ks++) {
    short8 a0 = *(const short8*)&A_lds[(w * 32 + l15) * 136 + ks * 32 + quad * 8];
    short8 a1 = *(const short8*)&A_lds[(w * 32 + 16 + l15) * 136 + ks * 32 + quad * 8];
#pragma unroll
    for (int ns = 0; ns < 4; ns++) {
      short8 bb = *(const short8*)&B_lds[(ns * 16 + l15) * 136 + ks * 32 + quad * 8];
      acc[0][ns] = __builtin_amdgcn_mfma_f32_16x16x32_bf16(a0, bb, acc[0][ns], 0, 0, 0);
      acc[1][ns] = __builtin_amdgcn_mfma_f32_16x16x32_bf16(a1, bb, acc[1][ns], 0, 0, 0);
    }
  }
#pragma unroll
  for (int ms = 0; ms < 2; ms++) {
    int o = o0 + w * 32 + ms * 16 + quad * 4;
#pragma unroll
    for (int ns = 0; ns < 4; ns++) {
      int n = n0 + ns * 16 + l15;
#pragma unroll
      for (int r = 0; r < 4; r++) {
        size_t off = ((size_t)(b * 512 + o + r)) * 4096 + n;
        out[off] = x[off] + acc[ms][ns][r];
      }
    }
  }
}

extern "C" void kernel_launch(void* const* d_in, const int* in_sizes, int n_in,
                              void* d_out, int out_size, void* d_ws, size_t ws_size,
                              hipStream_t stream) {
  const float* x = (const float*)d_in[0];
  const float* w_in = (const float*)d_in[1];
  const float* w_out = (const float*)d_in[2];
  float* out = (float*)d_out;

  unsigned short* ab = (unsigned short*)d_ws;                 // 8*4096*256 bf16
  unsigned short* gC = ab + (size_t)8 * 4096 * 256;           // 8*128*4096 bf16
  unsigned short* yt = gC + (size_t)8 * 128 * 4096;           // 8*4096*128 bf16

  k_proj<<<dim3(64, 3, 8), 256, 0, stream>>>(x, w_in, ab, gC);
  k_attn<<<dim3(64, 8), 256, 0, stream>>>(ab, gC, yt);
  k_out<<<dim3(64, 4, 8), 256, 0, stream>>>(x, w_out, yt, out);
}

// Round 4
// 235.647 us; speedup vs baseline: 2.1156x; 1.4631x over previous
//
#include <hip/hip_runtime.h>

// NonLocalBlock: B=8, C=512, N=4096 (64x64), CR=128.
// ws layout (bf16): ab [8][4096][256] (emb_a 0..127, emb_b 128..255, token-major)
//                   gC [8][128][4096] (channel-major)
//                   yt [8][4096][128] (token-major)
//                   wi [384][512]  (bf16 w_in, from k_prep)
//                   wo [512][128]  (bf16 w_out, from k_prep)

typedef __attribute__((ext_vector_type(8))) short short8;
typedef __attribute__((ext_vector_type(4))) float f32x4;
typedef __attribute__((ext_vector_type(16))) float f32x16;

__device__ inline unsigned bfr(float f) {   // bf16 round-half-up, result in high half
  union { float f; unsigned u; } v; v.f = f;
  return v.u + 0x8000u;
}
__device__ inline unsigned short f2bf(float f) { return (unsigned short)(bfr(f) >> 16); }
// pack2(a,b) -> [bf16(a) lo, bf16(b) hi] : 2 adds + 1 v_perm_b32
__device__ inline unsigned pack2(float a, float b) {
  return __builtin_amdgcn_perm(bfr(b), bfr(a), 0x07060302u);
}
// XOR-swizzled LDS index (halves). 16B granules: phys = g ^ (row&7).
__device__ inline int sw(int row, int col, int stride_halves) {
  return row * stride_halves + ((((col >> 3) ^ (row & 7)) << 3) | (col & 7));
}
// async global->LDS DMA, 16B per lane; lds dest = wave-uniform base + lane*16
__device__ inline void load_lds16(const void* g, void* l) {
  __builtin_amdgcn_global_load_lds(
      (const __attribute__((address_space(1))) unsigned int*)g,
      (__attribute__((address_space(3))) unsigned int*)l, 16, 0, 0);
}

// ---------------- kernel 0: weight precompute fp32 -> bf16 -------------------------
__global__ __launch_bounds__(256) void k_prep(const float* __restrict__ w_in,
                                              const float* __restrict__ w_out,
                                              unsigned short* __restrict__ wi,
                                              unsigned short* __restrict__ wo) {
  int i = blockIdx.x * 256 + threadIdx.x;   // 8 floats per thread; 32768 threads
  const float* src;
  unsigned short* dst;
  int base;
  if (i < 24576) { src = w_in;  dst = wi; base = i * 8; }           // 196608 elems
  else           { src = w_out; dst = wo; base = (i - 24576) * 8; } // 65536 elems
  float4 d0 = *(const float4*)&src[base];
  float4 d1 = *(const float4*)&src[base + 4];
  uint4 p;
  p.x = pack2(d0.x, d0.y); p.y = pack2(d0.z, d0.w);
  p.z = pack2(d1.x, d1.y); p.w = pack2(d1.z, d1.w);
  *(uint4*)&dst[base] = p;
}

// ---------------- kernel 1: in-projection GEMM (M=384, K=512, N=4096, per batch) ----
// A (weights) staged by DMA from prepped bf16; B (x) reg-transposed + packed.
__global__ __launch_bounds__(256) void k_proj(const float* __restrict__ x,
                                              const unsigned short* __restrict__ wi,
                                              unsigned short* __restrict__ ab,
                                              unsigned short* __restrict__ gC) {
  __shared__ unsigned short A_lds[128 * 64];   // [128 o][64 c], swizzled
  __shared__ unsigned short B_lds[64 * 64];    // [64 n][64 c], swizzled
  const int t = threadIdx.x;
  const int lane = t & 63;
  const int w = t >> 6;
  const int l15 = lane & 15;
  const int quad = lane >> 4;
  const int n0 = blockIdx.x * 64;
  const int o0 = blockIdx.y * 128;
  const int b = blockIdx.z;
  const int ch8g = t >> 5;        // 0..7: 8-channel group for B staging
  const int tp = t & 31;          // 0..31: token pair

  f32x4 acc[2][4];
#pragma unroll
  for (int i = 0; i < 2; i++)
#pragma unroll
    for (int j = 0; j < 4; j++) acc[i][j] = (f32x4)0.f;

  for (int k0 = 0; k0 < 512; k0 += 64) {
    // stage A via DMA: rows w*32+j*8+(lane>>3), phys granule lane&7, src granule xor'd
#pragma unroll
    for (int j = 0; j < 4; j++) {
      int row = w * 32 + j * 8 + (lane >> 3);
      int gs = (lane & 7) ^ (row & 7);
      load_lds16(&wi[(size_t)(o0 + row) * 512 + k0 + gs * 8],
                 (void*)&A_lds[(w * 32 + j * 8) * 64]);
    }
    // stage B micro-transpose: 8 channels x 2 tokens per thread
    {
      float2 d[8];
#pragma unroll
      for (int j = 0; j < 8; j++)
        d[j] = *(const float2*)&x[((size_t)(b * 512 + k0 + ch8g * 8 + j)) * 4096 + n0 + tp * 2];
#pragma unroll
      for (int i = 0; i < 2; i++) {
        int r = tp * 2 + i;
        uint4 pv;
        if (i == 0) {
          pv.x = pack2(d[0].x, d[1].x); pv.y = pack2(d[2].x, d[3].x);
          pv.z = pack2(d[4].x, d[5].x); pv.w = pack2(d[6].x, d[7].x);
        } else {
          pv.x = pack2(d[0].y, d[1].y); pv.y = pack2(d[2].y, d[3].y);
          pv.z = pack2(d[4].y, d[5].y); pv.w = pack2(d[6].y, d[7].y);
        }
        *(uint4*)&B_lds[sw(r, ch8g * 8, 64)] = pv;
      }
    }
    __syncthreads();
#pragma unroll
    for (int kk = 0; kk < 64; kk += 32) {
      short8 a0 = *(const short8*)&A_lds[sw(w * 32 + l15, kk + quad * 8, 64)];
      short8 a1 = *(const short8*)&A_lds[sw(w * 32 + 16 + l15, kk + quad * 8, 64)];
#pragma unroll
      for (int ns = 0; ns < 4; ns++) {
        short8 bb = *(const short8*)&B_lds[sw(ns * 16 + l15, kk + quad * 8, 64)];
        acc[0][ns] = __builtin_amdgcn_mfma_f32_16x16x32_bf16(a0, bb, acc[0][ns], 0, 0, 0);
        acc[1][ns] = __builtin_amdgcn_mfma_f32_16x16x32_bf16(a1, bb, acc[1][ns], 0, 0, 0);
      }
    }
    __syncthreads();
  }
  if (o0 < 256) {
#pragma unroll
    for (int ms = 0; ms < 2; ms++) {
      int o = o0 + w * 32 + ms * 16 + quad * 4;
#pragma unroll
      for (int ns = 0; ns < 4; ns++) {
        int n = n0 + ns * 16 + l15;
        uint2 p;
        p.x = pack2(acc[ms][ns][0], acc[ms][ns][1]);
        p.y = pack2(acc[ms][ns][2], acc[ms][ns][3]);
        *(uint2*)&ab[((size_t)(b * 4096 + n)) * 256 + o] = p;
      }
    }
  } else {
#pragma unroll
    for (int ms = 0; ms < 2; ms++) {
      int og = w * 32 + ms * 16 + quad * 4;
#pragma unroll
      for (int ns = 0; ns < 4; ns++) {
        int n = n0 + ns * 16 + l15;
#pragma unroll
        for (int r = 0; r < 4; r++)
          gC[((size_t)(b * 128 + og + r)) * 4096 + n] = f2bf(acc[ms][ns][r]);
      }
    }
  }
}

// ---------------- kernel 2: flash attention, 32x32x16 MFMA, DMA double-buffer -------
// Wave (wr=w&1, wc=w>>1): S^T tile [32 keys][32 q]; O^T partials merged in epilogue.
// Per iter: issue DMA for tile i+1 -> buf^1, compute tile i from buf, ONE barrier.
__global__ __launch_bounds__(256, 2) void k_attn(const unsigned short* __restrict__ ab,
                                                 const unsigned short* __restrict__ gC,
                                                 unsigned short* __restrict__ yt) {
  __shared__ uint4 smem4[65536 / 16];                       // 64 KB
  unsigned short* smem_h = (unsigned short*)smem4;
  // K bufs: halves [0, 8192), [8192, 16384);  V bufs: [16384, 24576), [24576, 32768)
  float* Obuf = (float*)smem4;                              // epilogue [64 q][129 c]
  float* lsumbuf = (float*)((char*)smem4 + 33024);          // [64]
  unsigned* Pbuf = (unsigned*)((char*)smem4 + 33280);       // [64 q][65]

  const int t = threadIdx.x;
  const int lane = t & 63;
  const int w = t >> 6;
  const int wr = w & 1;        // key half
  const int wc = w >> 1;       // q half
  const int l31 = lane & 31;
  const int h = lane >> 5;
  const int l7 = l31 & 7;
  const int q0 = blockIdx.x * 64;
  const int b = blockIdx.y;

  // Q fragments (B operand), loop-invariant
  short8 qf[8];
  {
    const unsigned short* qp = &ab[((size_t)(b * 4096 + q0 + wc * 32 + l31)) * 256 + h * 8];
#pragma unroll
    for (int ks = 0; ks < 8; ks++) qf[ks] = *(const short8*)&qp[ks * 16];
  }

  const int krow_c = w * 16 + (lane >> 4);   // K DMA row (+j*4)
  const int vrow_c = w * 32 + (lane >> 3);   // V DMA row (+j*8)

  auto dma_tile = [&](int kt, int buf) {
    unsigned short* Kb = smem_h + buf * 8192;
    unsigned short* Vb = smem_h + 16384 + buf * 8192;
#pragma unroll
    for (int j = 0; j < 4; j++) {            // K: [64 key][128 c] rows of 256 B
      int row = krow_c + j * 4;
      int gs = (lane & 15) ^ (row & 7);
      load_lds16(&ab[((size_t)(b * 4096 + kt + row)) * 256 + 128 + gs * 8],
                 (void*)&Kb[(w * 16 + j * 4) * 128]);
    }
#pragma unroll
    for (int j = 0; j < 4; j++) {            // V: [128 c][64 key] rows of 128 B
      int row = vrow_c + j * 8;
      int gs = (lane & 7) ^ (row & 7);
      load_lds16(&gC[((size_t)(b * 128 + row)) * 4096 + kt + gs * 8],
                 (void*)&Vb[(w * 32 + j * 8) * 64]);
    }
  };

  f32x16 O[4];
#pragma unroll
  for (int i = 0; i < 4; i++) O[i] = (f32x16)0.f;
  float lsum = 0.f;
  const int rowK = wr * 32 + l31;

  dma_tile(0, 0);
  __syncthreads();

  for (int it = 0; it < 64; ++it) {
    if (it < 63) dma_tile((it + 1) * 64, (it + 1) & 1);   // prefetch next tile (async)
    const unsigned short* Kc = smem_h + (it & 1) * 8192;
    const unsigned short* Vc = smem_h + 16384 + (it & 1) * 8192;

    // S^T = K · Q^T : D[key 32][q 32]
    f32x16 accS = (f32x16)0.f;
#pragma unroll
    for (int ks = 0; ks < 8; ks++) {
      short8 ak = *(const short8*)&Kc[rowK * 128 + (((ks * 2 + h) ^ l7) << 3)];
      accS = __builtin_amdgcn_mfma_f32_32x32x16_bf16(ak, qf[ks], accS, 0, 0, 0);
    }

    // exp (no max; scores bounded) + lsum partial
    float ps[16];
#pragma unroll
    for (int r = 0; r < 16; r++) {
      ps[r] = __expf(accS[r]);
      lsum += ps[r];
    }
    unsigned u[8];
#pragma unroll
    for (int i = 0; i < 8; i++) u[i] = pack2(ps[2 * i], ps[2 * i + 1]);

    // P^T B-frags in-register (C->A layout fixup via 2 shuffles per frag)
    short8 pfrag[2];
#pragma unroll
    for (int f = 0; f < 2; f++) {
      unsigned a0 = u[4 * f + 0], a1 = u[4 * f + 1], a2 = u[4 * f + 2], a3 = u[4 * f + 3];
      unsigned r0 = __shfl_xor(h ? a0 : a2, 32);
      unsigned r1 = __shfl_xor(h ? a1 : a3, 32);
      union { unsigned uu[4]; short8 s; } cv;
      if (h == 0) { cv.uu[0] = a0; cv.uu[1] = a1; cv.uu[2] = r0; cv.uu[3] = r1; }
      else        { cv.uu[0] = r0; cv.uu[1] = r1; cv.uu[2] = a2; cv.uu[3] = a3; }
      pfrag[f] = cv.s;
    }

    // O^T[c][q] += V · P^T over this wave's 32 keys
#pragma unroll
    for (int ct = 0; ct < 4; ct++) {
      int rowV = ct * 32 + l31;
#pragma unroll
      for (int f = 0; f < 2; f++) {
        short8 av = *(const short8*)&Vc[rowV * 64 + (((wr * 4 + f * 2 + h) ^ l7) << 3)];
        O[ct] = __builtin_amdgcn_mfma_f32_32x32x16_bf16(av, pfrag[f], O[ct], 0, 0, 0);
      }
    }
    __syncthreads();   // drains DMA (in flight during whole compute) + LDS reads
  }

  // ---- epilogue: merge key-half partials, normalize, coalesced store ----
  lsum += __shfl_xor(lsum, 32);
  const int q = wc * 32 + l31;
  if (wr == 0) {
#pragma unroll
    for (int ct = 0; ct < 4; ct++)
#pragma unroll
      for (int r = 0; r < 16; r++) {
        int c = ct * 32 + (r & 3) + 8 * (r >> 2) + 4 * h;
        Obuf[q * 129 + c] = O[ct][r];
      }
    if (h == 0) lsumbuf[q] = lsum;
  }
  __syncthreads();
  if (wr == 1) {
    float linv = 1.f / (lsum + lsumbuf[q]);
#pragma unroll
    for (int ct = 0; ct < 4; ct++)
#pragma unroll
      for (int r = 0; r < 16; r += 2) {
        int c = ct * 32 + (r & 3) + 8 * (r >> 2) + 4 * h;
        float v0 = (Obuf[q * 129 + c] + O[ct][r]) * linv;
        float v1 = (Obuf[q * 129 + c + 1] + O[ct][r + 1]) * linv;
        Pbuf[q * 65 + (c >> 1)] = pack2(v0, v1);
      }
  }
  __syncthreads();
  {
    int qq = t >> 2, seg = t & 3;
    unsigned* yrow = (unsigned*)&yt[((size_t)(b * 4096 + q0 + qq)) * 128];
#pragma unroll
    for (int i = 0; i < 4; i++) {
      uint4 v;
      v.x = Pbuf[qq * 65 + seg * 16 + i * 4 + 0];
      v.y = Pbuf[qq * 65 + seg * 16 + i * 4 + 1];
      v.z = Pbuf[qq * 65 + seg * 16 + i * 4 + 2];
      v.w = Pbuf[qq * 65 + seg * 16 + i * 4 + 3];
      *(uint4*)&yrow[seg * 16 + i * 4] = v;
    }
  }
}

// ---------------- kernel 3: out-projection GEMM (M=512, K=128, N=4096) + residual ---
// Both operands bf16 in ws -> staged 100% by DMA, zero conversion/ds_write VALU.
__global__ __launch_bounds__(256) void k_out(const float* __restrict__ x,
                                             const unsigned short* __restrict__ wo,
                                             const unsigned short* __restrict__ yt,
                                             float* __restrict__ out) {
  __shared__ unsigned short A_lds[128 * 128];  // [128 o][128 c], swizzled (32 KB)
  __shared__ unsigned short B_lds[64 * 128];   // [64 n][128 c], swizzled (16 KB)
  const int t = threadIdx.x;
  const int lane = t & 63;
  const int w = t >> 6;
  const int l15 = lane & 15;
  const int quad = lane >> 4;
  const int n0 = blockIdx.x * 64;
  const int o0 = blockIdx.y * 128;
  const int b = blockIdx.z;

  // A DMA: 8 calls x 4 rows (256 B rows)
#pragma unroll
  for (int j = 0; j < 8; j++) {
    int row = w * 32 + j * 4 + (lane >> 4);
    int gs = (lane & 15) ^ (row & 7);
    load_lds16(&wo[(size_t)(o0 + row) * 128 + gs * 8],
               (void*)&A_lds[(w * 32 + j * 4) * 128]);
  }
  // B DMA: 4 calls x 4 rows
#pragma unroll
  for (int j = 0; j < 4; j++) {
    int row = w * 16 + j * 4 + (lane >> 4);
    int gs = (lane & 15) ^ (row & 7);
    load_lds16(&yt[((size_t)(b * 4096 + n0 + row)) * 128 + gs * 8],
               (void*)&B_lds[(w * 16 + j * 4) * 128]);
  }
  __syncthreads();

  f32x4 acc[2][4];
#pragma unroll
  for (int i = 0; i < 2; i++)
#pragma unroll
    for (int j = 0; j < 4; j++) acc[i][j] = (f32x4)0.f;
#pragma unroll
  for (int ks = 0; ks < 4; ks++) {
    short8 a0 = *(const short8*)&A_lds[sw(w * 32 + l15, ks * 32 + quad * 8, 128)];
    short8 a1 = *(const short8*)&A_lds[sw(w * 32 + 16 + l15, ks * 32 + quad * 8, 128)];
#pragma unroll
    for (int ns = 0; ns < 4; ns++) {
      short8 bb = *(const short8*)&B_lds[sw(ns * 16 + l15, ks * 32 + quad * 8, 128)];
      acc[0][ns] = __builtin_amdgcn_mfma_f32_16x16x32_bf16(a0, bb, acc[0][ns], 0, 0, 0);
      acc[1][ns] = __builtin_amdgcn_mfma_f32_16x16x32_bf16(a1, bb, acc[1][ns], 0, 0, 0);
    }
  }
#pragma unroll
  for (int ms = 0; ms < 2; ms++) {
    int o = o0 + w * 32 + ms * 16 + quad * 4;
#pragma unroll
    for (int ns = 0; ns < 4; ns++) {
      int n = n0 + ns * 16 + l15;
#pragma unroll
      for (int r = 0; r < 4; r++) {
        size_t off = ((size_t)(b * 512 + o + r)) * 4096 + n;
        out[off] = x[off] + acc[ms][ns][r];
      }
    }
  }
}

extern "C" void kernel_launch(void* const* d_in, const int* in_sizes, int n_in,
                              void* d_out, int out_size, void* d_ws, size_t ws_size,
                              hipStream_t stream) {
  const float* x = (const float*)d_in[0];
  const float* w_in = (const float*)d_in[1];
  const float* w_out = (const float*)d_in[2];
  float* out = (float*)d_out;

  unsigned short* ab = (unsigned short*)d_ws;                 // 8*4096*256
  unsigned short* gC = ab + (size_t)8 * 4096 * 256;           // 8*128*4096
  unsigned short* yt = gC + (size_t)8 * 128 * 4096;           // 8*4096*128
  unsigned short* wi = yt + (size_t)8 * 4096 * 128;           // 384*512
  unsigned short* wo = wi + (size_t)384 * 512;                // 512*128

  k_prep<<<128, 256, 0, stream>>>(w_in, w_out, wi, wo);
  k_proj<<<dim3(64, 3, 8), 256, 0, stream>>>(x, wi, ab, gC);
  k_attn<<<dim3(64, 8), 256, 0, stream>>>(ab, gC, yt);
  k_out<<<dim3(64, 4, 8), 256, 0, stream>>>(x, wo, yt, out);
}